// Round 8
// baseline (317.633 us; speedup 1.0000x reference)
//
#include <hip/hip_runtime.h>
#include <stdint.h>

typedef unsigned short u16;
typedef __attribute__((ext_vector_type(8))) short short8;
typedef __attribute__((ext_vector_type(4))) float f32x4;
typedef __attribute__((ext_vector_type(16))) float f32x16;

#define B_ 2
#define S_ 2048
#define E_ 2048
#define H_ 16
#define D_ 128
#define M_ 4096

__device__ __forceinline__ u16 f2bf(float f) {
  unsigned u = __float_as_uint(f);
  u = u + 0x7FFFu + ((u >> 16) & 1u);
  return (u16)(u >> 16);
}
__device__ __forceinline__ float bf2f(u16 h) {
  return __uint_as_float(((unsigned)h) << 16);
}

// async global->LDS, 16B per lane; LDS dest is wave-uniform base + lane*16
#define GLD16(gp, lp) __builtin_amdgcn_global_load_lds(                      \
    (__attribute__((address_space(1))) void*)(gp),                           \
    (__attribute__((address_space(3))) void*)(lp), 16, 0, 0)

// ---------------------------------------------------------------- cast f32->bf16
__global__ void cast_bf16(const float4* __restrict__ src, ushort4* __restrict__ dst, int n4) {
  int i = blockIdx.x * 256 + threadIdx.x;
  if (i < n4) {
    float4 v = src[i];
    ushort4 o;
    o.x = f2bf(v.x); o.y = f2bf(v.y); o.z = f2bf(v.z); o.w = f2bf(v.w);
    dst[i] = o;
  }
}

// 4 weight casts in one launch (blockIdx.y selects the tensor); o0..o2 contiguous -> [Wq;Wk;Wv]
__global__ void cast4_bf16(const float4* __restrict__ w0, const float4* __restrict__ w1,
                           const float4* __restrict__ w2, const float4* __restrict__ w3,
                           ushort4* __restrict__ o0, ushort4* __restrict__ o1,
                           ushort4* __restrict__ o2, ushort4* __restrict__ o3, int n4) {
  const int i = blockIdx.x * 256 + threadIdx.x;
  if (i >= n4) return;
  const float4* s; ushort4* d;
  switch (blockIdx.y) {
    case 0: s = w0; d = o0; break;
    case 1: s = w1; d = o1; break;
    case 2: s = w2; d = o2; break;
    default: s = w3; d = o3; break;
  }
  float4 v = s[i];
  ushort4 o;
  o.x = f2bf(v.x); o.y = f2bf(v.y); o.z = f2bf(v.z); o.w = f2bf(v.w);
  d[i] = o;
}

// ---------------------------------------------------------------- GEMM v2.1: deep-pipelined, T2+T4+T5
// C = A[M,K] @ W[N,K]^T.  BM=128, BN=256, BK=64. 8 waves (512 thr), per-wave 64x64 output.
// 3-deep LDS ring (144 KB): compute tile t from buf t%3 while t+1,t+2 are in flight.
// One raw s_barrier + one counted s_waitcnt vmcnt(6) per K-tile (vmcnt(0) only on the last).
// T2: 128B LDS rows + XOR(chunk, row&7) swizzle via inverse-permuted global source.
// XCD swizzle v2 (round-8 fix): each XCD owns a COLUMN BAND of bxpx bx-panels x all by
// -> per-XCD B working set = bxpx MB (L2-resident), A panels reused by bxpx consecutive
// blocks. Requires gx == 8*bxpx. (v1's by-major chunks made each XCD touch all of B:
// FETCH 307 MB, memory-bound.)
// MODE 0: fused QKV (N=6144): tz = nn>>11 selects tensor; writes [B,H,S,D] bf16 at Cp + tz*NX.
// MODE 1: write f32 row-major [M,N].
template <int MODE>
__launch_bounds__(512, 1)
__global__ void gemm256(const u16* __restrict__ A, const u16* __restrict__ Bw,
                        void* __restrict__ Cp, int M, int N, int K, int bxpx) {
  __shared__ alignas(16) u16 LA[3][128 * 64];
  __shared__ alignas(16) u16 LB[3][256 * 64];
  const int tid = threadIdx.x, wave = tid >> 6, lane = tid & 63;
  const int xcd = blockIdx.x & 7;
  const int j = blockIdx.x >> 3;
  const int bx = xcd * bxpx + (j % bxpx);
  const int by = j / bxpx;
  const int m0 = by * 128, n0 = bx * 256;
  const int wm = (wave >> 2) * 64, wn = (wave & 3) * 64;
  const int lrow = lane & 15, lq = lane >> 4;

  auto stageA = [&](int buf, int kt) {   // A tile (2 issues) + B issue 0
    const int k0 = kt * 64;
#pragma unroll
    for (int i = 0; i < 2; ++i) {
      const int c = i * 512 + tid;
      const int row = c >> 3, k = c & 7;
      GLD16(A + (size_t)(m0 + row) * K + k0 + ((k ^ (row & 7)) * 8),
            &LA[buf][i * 4096 + wave * 512]);
    }
    {
      const int c = tid;
      const int row = c >> 3, k = c & 7;
      GLD16(Bw + (size_t)(n0 + row) * K + k0 + ((k ^ (row & 7)) * 8),
            &LB[buf][wave * 512]);
    }
  };
  auto stageB = [&](int buf, int kt) {   // B issues 1..3
    const int k0 = kt * 64;
#pragma unroll
    for (int i = 1; i < 4; ++i) {
      const int c = i * 512 + tid;
      const int row = c >> 3, k = c & 7;
      GLD16(Bw + (size_t)(n0 + row) * K + k0 + ((k ^ (row & 7)) * 8),
            &LB[buf][i * 4096 + wave * 512]);
    }
  };

  f32x4 acc[4][4] = {};
  const int NT = K >> 6;                 // 32
  stageA(0, 0); stageB(0, 0);
  stageA(1, 1); stageB(1, 1);

  for (int t = 0; t < NT; ++t) {
    if (t < NT - 1) { asm volatile("s_waitcnt vmcnt(6)" ::: "memory"); }
    else           { asm volatile("s_waitcnt vmcnt(0)" ::: "memory"); }
    __builtin_amdgcn_sched_barrier(0);
    __builtin_amdgcn_s_barrier();
    __builtin_amdgcn_sched_barrier(0);
    const int cur = t % 3;
    const int sb = (t + 2) % 3;
    const bool dostage = (t + 2) < NT;

#pragma unroll
    for (int kk = 0; kk < 2; ++kk) {
      if (dostage) { if (kk == 0) stageA(sb, t + 2); else stageB(sb, t + 2); }
      short8 a[4], b[4];
#pragma unroll
      for (int m = 0; m < 4; ++m) {
        const int row = wm + m * 16 + lrow;
        const int c = kk * 4 + lq;
        a[m] = *(const short8*)&LA[cur][row * 64 + ((c ^ (row & 7)) * 8)];
      }
#pragma unroll
      for (int n = 0; n < 4; ++n) {
        const int row = wn + n * 16 + lrow;
        const int c = kk * 4 + lq;
        b[n] = *(const short8*)&LB[cur][row * 64 + ((c ^ (row & 7)) * 8)];
      }
      __builtin_amdgcn_s_setprio(1);
#pragma unroll
      for (int m = 0; m < 4; ++m)
#pragma unroll
        for (int n = 0; n < 4; ++n)
          acc[m][n] = __builtin_amdgcn_mfma_f32_16x16x32_bf16(a[m], b[n], acc[m][n], 0, 0, 0);
      __builtin_amdgcn_s_setprio(0);
    }
  }

  const int rbase = lq * 4;  // C/D: col = lane&15, row = (lane>>4)*4 + r
#pragma unroll
  for (int m = 0; m < 4; ++m)
#pragma unroll
    for (int n = 0; n < 4; ++n)
#pragma unroll
      for (int r = 0; r < 4; ++r) {
        const int mm = m0 + wm + m * 16 + rbase + r;
        const int nn = n0 + wn + n * 16 + lrow;
        const float v = acc[m][n][r];
        if (MODE == 0) {
          const size_t NXc = (size_t)B_ * S_ * E_;
          const int bb = mm >> 11, s = mm & (S_ - 1);
          const int tz = nn >> 11, nc = nn & 2047;      // tile fully inside one tensor
          const int h = nc >> 7, d = nc & (D_ - 1);
          ((u16*)Cp)[(size_t)tz * NXc + (((size_t)bb * H_ + h) * S_ + s) * D_ + d] = f2bf(v);
        } else {
          ((float*)Cp)[(size_t)mm * N + nn] = v;
        }
      }
}

// ---------------------------------------------------------------- RoPE (NeoX) in-place on Q and K, [B,H,S,D] bf16
// Vectorized: 8 d-elements per thread. Q additionally pre-scaled by (1/sqrt(D))*log2(e).
__global__ void rope2_k(u16* __restrict__ Qb, u16* __restrict__ Kb,
                        const float* __restrict__ cosT, const float* __restrict__ sinT) {
  const int y = blockIdx.y;
  u16* T = y ? Kb : Qb;
  const float sc = y ? 1.f : 0.12751744154f;  // 0.0883883476 * 1.4426950409
  const int idx = blockIdx.x * 256 + threadIdx.x;  // B*H*S*8 threads per tensor
  const int row = idx >> 3;                        // (b*H+h)*S + s
  const int d0 = (idx & 7) * 8;
  const int s = row & (S_ - 1);
  const size_t base = (size_t)row * D_;
  short8 lo = *(const short8*)&T[base + d0];
  short8 hv = *(const short8*)&T[base + d0 + 64];
  float c1v[8], s1v[8], c2v[8], s2v[8];
  *(float4*)&c1v[0] = *(const float4*)&cosT[s * D_ + d0];
  *(float4*)&c1v[4] = *(const float4*)&cosT[s * D_ + d0 + 4];
  *(float4*)&s1v[0] = *(const float4*)&sinT[s * D_ + d0];
  *(float4*)&s1v[4] = *(const float4*)&sinT[s * D_ + d0 + 4];
  *(float4*)&c2v[0] = *(const float4*)&cosT[s * D_ + d0 + 64];
  *(float4*)&c2v[4] = *(const float4*)&cosT[s * D_ + d0 + 68];
  *(float4*)&s2v[0] = *(const float4*)&sinT[s * D_ + d0 + 64];
  *(float4*)&s2v[4] = *(const float4*)&sinT[s * D_ + d0 + 68];
  short8 olo, ohi;
#pragma unroll
  for (int j = 0; j < 8; ++j) {
    const float x1 = bf2f((u16)lo[j]), x2 = bf2f((u16)hv[j]);
    olo[j] = (short)f2bf((x1 * c1v[j] - x2 * s1v[j]) * sc);
    ohi[j] = (short)f2bf((x2 * c2v[j] + x1 * s2v[j]) * sc);
  }
  *(short8*)&T[base + d0] = olo;
  *(short8*)&T[base + d0 + 64] = ohi;
}

// ---------------------------------------------------------------- V [B,H,S,D] -> VT [B,H,D,S]
__global__ void transpose64(const u16* __restrict__ V, u16* __restrict__ VT) {
  __shared__ alignas(16) u16 t[64][72];
  const int bh = blockIdx.z, st = blockIdx.y * 64, dt = blockIdx.x * 64;
  const u16* Vp = V + (size_t)bh * S_ * D_;
  u16* Tp = VT + (size_t)bh * D_ * S_;
  const int tid = threadIdx.x;
#pragma unroll
  for (int p = 0; p < 2; ++p) {
    const int idx = p * 256 + tid;
    const int r = idx >> 3, c8 = (idx & 7) * 8;
    *(short8*)&t[r][c8] = *(const short8*)&Vp[(size_t)(st + r) * D_ + dt + c8];
  }
  __syncthreads();
#pragma unroll
  for (int p = 0; p < 2; ++p) {
    const int idx = p * 256 + tid;
    const int dr = idx >> 3, s8 = (idx & 7) * 8;
    short8 v;
#pragma unroll
    for (int j = 0; j < 8; ++j) v[j] = t[s8 + j][dr];
    *(short8*)&Tp[(size_t)(dt + dr) * S_ + st + s8] = v;
  }
}

// ---------------------------------------------------------------- causal flash attention v4 (proven: 82 us)
// 8 waves x 32q, KV-parity split: waves 0-3 (grp A) even KV64 tiles, waves 4-7 (grp B) odd
// tiles, SAME 128 q-rows, concurrently (2 waves/SIMD). Each group has its own double-buffered
// K/V LDS stream. nt = 2t+2 (even) -> both groups do exactly t+1 steps: barriers uniform.
// Partial (m,l,O) merged through LDS at segment end. mr init = 0 (not -1e30) so a fully
// causal-masked first tile in group B yields p = exp2(-1e30-0) = 0, not exp2(0) = 1.
__launch_bounds__(512, 2)
__global__ void attn_fwd(const u16* __restrict__ Q, const u16* __restrict__ Kt,
                         const u16* __restrict__ VT, u16* __restrict__ Out) {
  // SB[stream][buf]: K tile [64][128] (8192 u16) then V^T tile [128][64] (8192 u16)
  __shared__ alignas(16) u16 SB[2][2][16384];
  __shared__ float MLB[4][64][2];
  const int tid = threadIdx.x, wave = tid >> 6, lane = tid & 63;
  // bijective XCD swizzle (256 % 8 == 0): 4 heads per XCD
  const int hw = blockIdx.x;
  const int lid = (hw & 7) * 32 + (hw >> 3);
  const int p = lid & 7, bh = lid >> 3;
  const int bb = bh >> 4, h = bh & 15;
  const u16* Qh = Q + (size_t)bh * S_ * D_;
  const u16* Kh = Kt + (size_t)bh * S_ * D_;
  const u16* Vh = VT + (size_t)bh * D_ * S_;
  const int grp = wave >> 2, w4 = wave & 3;
  const int l31 = lane & 31, hi = lane >> 5;

  auto stage = [&](int buf, int kv0) {   // 4 waves of my group stage my stream
#pragma unroll
    for (int pp = 0; pp < 4; ++pp) {
      const int g = pp * 4 + w4;       // 0..15 (wave-uniform)
      const int c = g * 64 + lane;     // 0..1023
      const int srow = c >> 4, dch = c & 15;
      GLD16(Kh + (size_t)(kv0 + srow) * D_ + ((dch ^ (srow & 7)) * 8), &SB[grp][buf][g * 512]);
      const int drow = c >> 3, sch = c & 7;
      GLD16(Vh + (size_t)drow * S_ + kv0 + ((sch ^ (drow & 7)) * 8), &SB[grp][buf][8192 + g * 512]);
    }
  };

  float* obuf = (float*)&SB[1][0][0];  // 64 KB merge region (stream 1, both buffers)

  const int qts[2] = {15 - p, p};
#pragma unroll 1
  for (int seg = 0; seg < 2; ++seg) {
    const int t = qts[seg];
    const int iters = t + 1;           // nt = 2t+2 KV64 tiles, split by parity
    const int q0 = t * 128 + w4 * 32;
    const int qg = q0 + l31;

    // Q fragments (B-operand): lane holds Q[qg][m*16 + hi*8 + j], j=0..7
    short8 qf[8];
#pragma unroll
    for (int m = 0; m < 8; ++m)
      qf[m] = *(const short8*)&Qh[(size_t)qg * D_ + m * 16 + hi * 8];

    f32x16 od[4] = {};   // out^T: od[dt], d = dt*32 + (reg&3)+8*(reg>>2)+4*hi, col q = l31
    float mr = 0.f, lsum = 0.f;        // mr init 0: see header comment

    stage(0, grp * 64);                // my first tile = tile grp
    int cur = 0;

    for (int i = 0; i < iters; ++i) {
      __syncthreads();  // both streams' buf[cur] staged; prior reads of buf[cur^1] done
      if (i + 1 < iters) stage(cur ^ 1, (2 * (i + 1) + grp) * 64);
      const int kv0 = (2 * i + grp) * 64;
      const u16* Kc = &SB[grp][cur][0];
      const u16* Vc = &SB[grp][cur][8192];

      // QK^T swapped: S^T[k][q], two 32-kv halves
      f32x16 s0 = {}, s1 = {};
      __builtin_amdgcn_s_setprio(1);
#pragma unroll
      for (int m = 0; m < 8; ++m) {
        const int col = m * 16 + hi * 8;
        const int sw = (l31 & 7) << 3;
        short8 k0 = *(const short8*)&Kc[l31 * 128 + (col ^ sw)];
        short8 k1 = *(const short8*)&Kc[(32 + l31) * 128 + (col ^ sw)];
        s0 = __builtin_amdgcn_mfma_f32_32x32x16_bf16(k0, qf[m], s0, 0, 0, 0);
        s1 = __builtin_amdgcn_mfma_f32_32x32x16_bf16(k1, qf[m], s1, 0, 0, 0);
      }
      __builtin_amdgcn_s_setprio(0);

      // causal mask (only tiles overlapping this wave's diagonal)
      if (kv0 + 63 > q0) {
#pragma unroll
        for (int r = 0; r < 16; ++r) {
          const int k0g = kv0 + (r & 3) + 8 * (r >> 2) + 4 * hi;
          if (k0g > qg)      s0[r] = -1e30f;
          if (k0g + 32 > qg) s1[r] = -1e30f;
        }
      }

      // online softmax (scores already in log2 units via pre-scaled Q)
      float mloc = s0[0];
#pragma unroll
      for (int r = 1; r < 16; ++r) mloc = fmaxf(mloc, s0[r]);
#pragma unroll
      for (int r = 0; r < 16; ++r) mloc = fmaxf(mloc, s1[r]);
      const float mx = fmaxf(mloc, __shfl_xor(mloc, 32));
      const bool need = !__all(mx <= mr + 8.f);   // defer-max (T13)
      float corr = 1.f;
      if (need) {
        const float mnew = fmaxf(mr, mx);
        corr = exp2f(mr - mnew);
        mr = mnew;
      }
      float sloc = 0.f;
#pragma unroll
      for (int r = 0; r < 16; ++r) { s0[r] = exp2f(s0[r] - mr); sloc += s0[r]; }
#pragma unroll
      for (int r = 0; r < 16; ++r) { s1[r] = exp2f(s1[r] - mr); sloc += s1[r]; }
      const float rsum = sloc + __shfl_xor(sloc, 32);
      lsum = lsum * corr + rsum;
      if (need) {
#pragma unroll
        for (int dt = 0; dt < 4; ++dt)
#pragma unroll
          for (int r = 0; r < 16; ++r) od[dt][r] *= corr;
      }

      // pack P to bf16 words: W[half][c][pr] covers k32 = 8c + 4hi + {2pr, 2pr+1}
      unsigned W0[4][2], W1[4][2];
#pragma unroll
      for (int c = 0; c < 4; ++c)
#pragma unroll
        for (int pr = 0; pr < 2; ++pr) {
          asm("v_cvt_pk_bf16_f32 %0, %1, %2"
              : "=v"(W0[c][pr]) : "v"(s0[4 * c + 2 * pr]), "v"(s0[4 * c + 2 * pr + 1]));
          asm("v_cvt_pk_bf16_f32 %0, %1, %2"
              : "=v"(W1[c][pr]) : "v"(s1[4 * c + 2 * pr]), "v"(s1[4 * c + 2 * pr + 1]));
        }

      // PV: out^T += V^T * P^T ; B-frag for group kk needs k = kk*16 + hi*8 + j
      __builtin_amdgcn_s_setprio(1);
#pragma unroll
      for (int kk = 0; kk < 4; ++kk) {
        const int cown = 2 * (kk & 1) + hi, csend = 2 * (kk & 1) + 1 - hi;
        unsigned o0, o1, sd0, sd1;
        if (kk < 2) { o0 = W0[cown][0]; o1 = W0[cown][1]; sd0 = W0[csend][0]; sd1 = W0[csend][1]; }
        else        { o0 = W1[cown][0]; o1 = W1[cown][1]; sd0 = W1[csend][0]; sd1 = W1[csend][1]; }
        const unsigned r0 = (unsigned)__shfl_xor((int)sd0, 32);
        const unsigned r1 = (unsigned)__shfl_xor((int)sd1, 32);
        uint4 bw;
        if (hi == 0) bw = make_uint4(o0, o1, r0, r1);
        else         bw = make_uint4(r0, r1, o0, o1);
        const short8 pf = *(const short8*)&bw;
        const int slot = 2 * kk + hi;
#pragma unroll
        for (int dt = 0; dt < 4; ++dt) {
          const int row = dt * 32 + l31;
          const short8 vf = *(const short8*)&Vc[row * 64 + ((slot ^ (row & 7)) * 8)];
          od[dt] = __builtin_amdgcn_mfma_f32_32x32x16_bf16(vf, pf, od[dt], 0, 0, 0);
        }
      }
      __builtin_amdgcn_s_setprio(0);
      cur ^= 1;
    }

    // ---- merge the two parity partials (group B -> LDS -> group A combines) ----
    __syncthreads();                     // all computes done; stream-1 LDS reusable
    if (grp == 1) {
      MLB[w4][lane][0] = mr;
      MLB[w4][lane][1] = lsum;
#pragma unroll
      for (int dt = 0; dt < 4; ++dt)
#pragma unroll
        for (int r = 0; r < 16; ++r)
          obuf[(dt * 16 + r) * 256 + w4 * 64 + lane] = od[dt][r];  // lane-major: conflict-free
    }
    __syncthreads();
    if (grp == 0) {
      const float mB = MLB[w4][lane][0];
      const float lB = MLB[w4][lane][1];
      const float m = fmaxf(mr, mB);
      const float aA = exp2f(mr - m), aB = exp2f(mB - m);
      lsum = lsum * aA + lB * aB;
#pragma unroll
      for (int dt = 0; dt < 4; ++dt)
#pragma unroll
        for (int r = 0; r < 16; ++r)
          od[dt][r] = od[dt][r] * aA + obuf[(dt * 16 + r) * 256 + w4 * 64 + lane] * aB;

      // finalize: o /= l, write bf16 to attn buffer laid out [B,S,E]
      const float inv = 1.f / lsum;
      const size_t obase = ((size_t)bb * S_ + qg) * E_ + h * D_;
#pragma unroll
      for (int dt = 0; dt < 4; ++dt)
#pragma unroll
        for (int g = 0; g < 4; ++g) {
          ushort4 w;
          w.x = f2bf(od[dt][4 * g + 0] * inv);
          w.y = f2bf(od[dt][4 * g + 1] * inv);
          w.z = f2bf(od[dt][4 * g + 2] * inv);
          w.w = f2bf(od[dt][4 * g + 3] * inv);
          *(ushort4*)&Out[obase + dt * 32 + 8 * g + 4 * hi] = w;
        }
    }
    __syncthreads();                     // merge reads done before next seg restages SB
  }
}

// ---------------------------------------------------------------- launcher
extern "C" void kernel_launch(void* const* d_in, const int* in_sizes, int n_in,
                              void* d_out, int out_size, void* d_ws, size_t ws_size,
                              hipStream_t stream) {
  const float* x    = (const float*)d_in[0];
  const float* cosT = (const float*)d_in[1];
  const float* sinT = (const float*)d_in[2];
  const float* Wq   = (const float*)d_in[3];
  const float* Wk   = (const float*)d_in[4];
  const float* Wv   = (const float*)d_in[5];
  const float* Wo   = (const float*)d_in[6];
  float* out = (float*)d_out;

  const size_t NX = (size_t)B_ * S_ * E_;  // 8388608
  const size_t NW = (size_t)E_ * E_;       // 4194304
  u16* ws  = (u16*)d_ws;
  u16* xb  = ws;
  u16* Wqb = xb + NX;        // [Wq;Wk;Wv] contiguous -> fused [6144][2048]
  u16* Wkb = Wqb + NW;
  u16* Wvb = Wkb + NW;
  u16* Wob = Wvb + NW;
  u16* Qb  = Wob + NW;       // Qb, Kb, Vb contiguous (gemm MODE 0 writes tz*NX offsets)
  u16* Kb  = Qb + NX;
  u16* Vb  = Kb + NX;
  u16* VTb = Vb + NX;
  u16* Ab  = VTb + NX;

  cast_bf16<<<(int)(NX / 4 / 256), 256, 0, stream>>>((const float4*)x, (ushort4*)xb, (int)(NX / 4));
  cast4_bf16<<<dim3((int)(NW / 4 / 256), 4), 256, 0, stream>>>(
      (const float4*)Wq, (const float4*)Wk, (const float4*)Wv, (const float4*)Wo,
      (ushort4*)Wqb, (ushort4*)Wkb, (ushort4*)Wvb, (ushort4*)Wob, (int)(NW / 4));

  // fused QKV projection: [4096,2048] x [6144,2048]^T -> Q,K,V all [B,H,S,D]
  gemm256<0><<<dim3(768), 512, 0, stream>>>(xb, Wqb, Qb, M_, 3 * E_, E_, 3);

  rope2_k<<<dim3((B_ * H_ * S_ * 8) / 256, 2), 256, 0, stream>>>(Qb, Kb, cosT, sinT);

  transpose64<<<dim3(D_ / 64, S_ / 64, B_ * H_), 256, 0, stream>>>(Vb, VTb);

  attn_fwd<<<dim3(256), 512, 0, stream>>>(Qb, Kb, VTb, Ab);

  gemm256<1><<<dim3(256), 512, 0, stream>>>(Ab, Wob, out, M_, E_, E_, 1);
}

// Round 9
// 271.885 us; speedup vs baseline: 1.1683x; 1.1683x over previous
//
#include <hip/hip_runtime.h>
#include <stdint.h>

typedef unsigned short u16;
typedef __attribute__((ext_vector_type(8))) short short8;
typedef __attribute__((ext_vector_type(4))) float f32x4;
typedef __attribute__((ext_vector_type(16))) float f32x16;

#define B_ 2
#define S_ 2048
#define E_ 2048
#define H_ 16
#define D_ 128
#define M_ 4096

__device__ __forceinline__ u16 f2bf(float f) {
  unsigned u = __float_as_uint(f);
  u = u + 0x7FFFu + ((u >> 16) & 1u);
  return (u16)(u >> 16);
}
__device__ __forceinline__ float bf2f(u16 h) {
  return __uint_as_float(((unsigned)h) << 16);
}

// async global->LDS, 16B per lane; LDS dest is wave-uniform base + lane*16
#define GLD16(gp, lp) __builtin_amdgcn_global_load_lds(                      \
    (__attribute__((address_space(1))) void*)(gp),                           \
    (__attribute__((address_space(3))) void*)(lp), 16, 0, 0)

// ---------------------------------------------------------------- cast f32->bf16
__global__ void cast_bf16(const float4* __restrict__ src, ushort4* __restrict__ dst, int n4) {
  int i = blockIdx.x * 256 + threadIdx.x;
  if (i < n4) {
    float4 v = src[i];
    ushort4 o;
    o.x = f2bf(v.x); o.y = f2bf(v.y); o.z = f2bf(v.z); o.w = f2bf(v.w);
    dst[i] = o;
  }
}

// 4 weight casts in one launch (blockIdx.y selects the tensor); o0..o2 contiguous -> [Wq;Wk;Wv]
__global__ void cast4_bf16(const float4* __restrict__ w0, const float4* __restrict__ w1,
                           const float4* __restrict__ w2, const float4* __restrict__ w3,
                           ushort4* __restrict__ o0, ushort4* __restrict__ o1,
                           ushort4* __restrict__ o2, ushort4* __restrict__ o3, int n4) {
  const int i = blockIdx.x * 256 + threadIdx.x;
  if (i >= n4) return;
  const float4* s; ushort4* d;
  switch (blockIdx.y) {
    case 0: s = w0; d = o0; break;
    case 1: s = w1; d = o1; break;
    case 2: s = w2; d = o2; break;
    default: s = w3; d = o3; break;
  }
  float4 v = s[i];
  ushort4 o;
  o.x = f2bf(v.x); o.y = f2bf(v.y); o.z = f2bf(v.z); o.w = f2bf(v.w);
  d[i] = o;
}

// ---------------------------------------------------------------- GEMM v3: phased schedule (T2+T3+T4+T5)
// C = A[M,K] @ W[N,K]^T.  BM=128, BN=256, BK=64. 8 waves, per-wave 64x64 output.
// 3-deep LDS ring (144 KB). Per K-tile: TWO phases (kk=0,1), each
// {8x ds_read_b128 frags + 3 staging issues -> s_barrier -> setprio(1) 16 MFMA setprio(0)
//  -> s_barrier}. Raw barriers (no waitcnt drain). Counted vmcnt certifies the ring:
//   prologue: stage tiles 0,1 (12 loads) -> vmcnt(6) [tile0 done] -> barrier.
//   tile t phase B: after stage1 issues, wait vmcnt(6) if t<=NT-3 (outstanding = tile t+1's 6
//   + tile t+2's <=6 -> <=6 left means t+1 done), vmcnt(0) at t==NT-2, none at NT-1.
//   Trailing barrier of tile t-1 publishes buf[t%3] for tile t's phase-A ds_reads.
// T2: XOR(chunk,row&7) swizzle via inverse-permuted global source; conflicts measured 0.
// XCD swizzle: column bands (bxpx panels per XCD), requires gridDim.x == 8*bxpx*rows.
// MODE 0: fused QKV (N=6144): tz=nn>>11 selects tensor; writes [B,H,S,D] bf16 at Cp+tz*NX.
// MODE 1: write f32 row-major [M,N].
template <int MODE>
__launch_bounds__(512, 1)
__global__ void gemm256(const u16* __restrict__ A, const u16* __restrict__ Bw,
                        void* __restrict__ Cp, int M, int N, int K, int bxpx) {
  __shared__ alignas(16) u16 LA[3][128 * 64];
  __shared__ alignas(16) u16 LB[3][256 * 64];
  const int tid = threadIdx.x, wave = tid >> 6, lane = tid & 63;
  const int xcd = blockIdx.x & 7;
  const int j = blockIdx.x >> 3;
  const int bx = xcd * bxpx + (j % bxpx);
  const int by = j / bxpx;
  const int m0 = by * 128, n0 = bx * 256;
  const int wm = (wave >> 2) * 64, wn = (wave & 3) * 64;
  const int lrow = lane & 15, lq = lane >> 4;

  auto stage0 = [&](int buf, int kt) {   // A tile (2 issues) + B issue 0   -> 3 loads/wave
    const int k0 = kt * 64;
#pragma unroll
    for (int i = 0; i < 2; ++i) {
      const int c = i * 512 + tid;
      const int row = c >> 3, k = c & 7;
      GLD16(A + (size_t)(m0 + row) * K + k0 + ((k ^ (row & 7)) * 8),
            &LA[buf][i * 4096 + wave * 512]);
    }
    {
      const int c = tid;
      const int row = c >> 3, k = c & 7;
      GLD16(Bw + (size_t)(n0 + row) * K + k0 + ((k ^ (row & 7)) * 8),
            &LB[buf][wave * 512]);
    }
  };
  auto stage1 = [&](int buf, int kt) {   // B issues 1..3                   -> 3 loads/wave
    const int k0 = kt * 64;
#pragma unroll
    for (int i = 1; i < 4; ++i) {
      const int c = i * 512 + tid;
      const int row = c >> 3, k = c & 7;
      GLD16(Bw + (size_t)(n0 + row) * K + k0 + ((k ^ (row & 7)) * 8),
            &LB[buf][i * 4096 + wave * 512]);
    }
  };

  f32x4 acc[4][4] = {};
  const int NT = K >> 6;                 // 32
  stage0(0, 0); stage1(0, 0);
  stage0(1, 1); stage1(1, 1);
  asm volatile("s_waitcnt vmcnt(6)" ::: "memory");   // tile 0's 6 loads done
  __builtin_amdgcn_sched_barrier(0);
  __builtin_amdgcn_s_barrier();                      // buf0 published to all waves

  for (int t = 0; t < NT; ++t) {
    const int cur = t % 3;
    const int sb = (t + 2) % 3;
    const bool dostage = (t + 2) < NT;

    // ===== phase A (k-chunk 0) =====
    short8 a0[4], b0[4];
#pragma unroll
    for (int m = 0; m < 4; ++m) {
      const int row = wm + m * 16 + lrow;
      a0[m] = *(const short8*)&LA[cur][row * 64 + ((lq ^ (row & 7)) * 8)];
    }
#pragma unroll
    for (int n = 0; n < 4; ++n) {
      const int row = wn + n * 16 + lrow;
      b0[n] = *(const short8*)&LB[cur][row * 64 + ((lq ^ (row & 7)) * 8)];
    }
    if (dostage) stage0(sb, t + 2);
    __builtin_amdgcn_sched_barrier(0);
    __builtin_amdgcn_s_barrier();
    __builtin_amdgcn_sched_barrier(0);
    __builtin_amdgcn_s_setprio(1);
#pragma unroll
    for (int m = 0; m < 4; ++m)
#pragma unroll
      for (int n = 0; n < 4; ++n)
        acc[m][n] = __builtin_amdgcn_mfma_f32_16x16x32_bf16(a0[m], b0[n], acc[m][n], 0, 0, 0);
    __builtin_amdgcn_s_setprio(0);
    __builtin_amdgcn_sched_barrier(0);
    __builtin_amdgcn_s_barrier();

    // ===== phase B (k-chunk 1) =====
    short8 a1[4], b1[4];
#pragma unroll
    for (int m = 0; m < 4; ++m) {
      const int row = wm + m * 16 + lrow;
      a1[m] = *(const short8*)&LA[cur][row * 64 + (((4 + lq) ^ (row & 7)) * 8)];
    }
#pragma unroll
    for (int n = 0; n < 4; ++n) {
      const int row = wn + n * 16 + lrow;
      b1[n] = *(const short8*)&LB[cur][row * 64 + (((4 + lq) ^ (row & 7)) * 8)];
    }
    if (dostage) stage1(sb, t + 2);
    if (t < NT - 2)      { asm volatile("s_waitcnt vmcnt(6)" ::: "memory"); }  // next tile certified
    else if (t == NT - 2){ asm volatile("s_waitcnt vmcnt(0)" ::: "memory"); }  // last tile: drain
    __builtin_amdgcn_sched_barrier(0);
    __builtin_amdgcn_s_barrier();
    __builtin_amdgcn_sched_barrier(0);
    __builtin_amdgcn_s_setprio(1);
#pragma unroll
    for (int m = 0; m < 4; ++m)
#pragma unroll
      for (int n = 0; n < 4; ++n)
        acc[m][n] = __builtin_amdgcn_mfma_f32_16x16x32_bf16(a1[m], b1[n], acc[m][n], 0, 0, 0);
    __builtin_amdgcn_s_setprio(0);
    __builtin_amdgcn_sched_barrier(0);
    __builtin_amdgcn_s_barrier();       // publishes buf[(t+1)%3] reads-safe + staging order
  }

  const int rbase = lq * 4;  // C/D: col = lane&15, row = (lane>>4)*4 + r
#pragma unroll
  for (int m = 0; m < 4; ++m)
#pragma unroll
    for (int n = 0; n < 4; ++n)
#pragma unroll
      for (int r = 0; r < 4; ++r) {
        const int mm = m0 + wm + m * 16 + rbase + r;
        const int nn = n0 + wn + n * 16 + lrow;
        const float v = acc[m][n][r];
        if (MODE == 0) {
          const size_t NXc = (size_t)B_ * S_ * E_;
          const int bb = mm >> 11, s = mm & (S_ - 1);
          const int tz = nn >> 11, nc = nn & 2047;      // tile fully inside one tensor
          const int h = nc >> 7, d = nc & (D_ - 1);
          ((u16*)Cp)[(size_t)tz * NXc + (((size_t)bb * H_ + h) * S_ + s) * D_ + d] = f2bf(v);
        } else {
          ((float*)Cp)[(size_t)mm * N + nn] = v;
        }
      }
}

// ---------------------------------------------------------------- RoPE (NeoX) in-place on Q and K, [B,H,S,D] bf16
// Vectorized: 8 d-elements per thread. Q additionally pre-scaled by (1/sqrt(D))*log2(e).
__global__ void rope2_k(u16* __restrict__ Qb, u16* __restrict__ Kb,
                        const float* __restrict__ cosT, const float* __restrict__ sinT) {
  const int y = blockIdx.y;
  u16* T = y ? Kb : Qb;
  const float sc = y ? 1.f : 0.12751744154f;  // 0.0883883476 * 1.4426950409
  const int idx = blockIdx.x * 256 + threadIdx.x;  // B*H*S*8 threads per tensor
  const int row = idx >> 3;                        // (b*H+h)*S + s
  const int d0 = (idx & 7) * 8;
  const int s = row & (S_ - 1);
  const size_t base = (size_t)row * D_;
  short8 lo = *(const short8*)&T[base + d0];
  short8 hv = *(const short8*)&T[base + d0 + 64];
  float c1v[8], s1v[8], c2v[8], s2v[8];
  *(float4*)&c1v[0] = *(const float4*)&cosT[s * D_ + d0];
  *(float4*)&c1v[4] = *(const float4*)&cosT[s * D_ + d0 + 4];
  *(float4*)&s1v[0] = *(const float4*)&sinT[s * D_ + d0];
  *(float4*)&s1v[4] = *(const float4*)&sinT[s * D_ + d0 + 4];
  *(float4*)&c2v[0] = *(const float4*)&cosT[s * D_ + d0 + 64];
  *(float4*)&c2v[4] = *(const float4*)&cosT[s * D_ + d0 + 68];
  *(float4*)&s2v[0] = *(const float4*)&sinT[s * D_ + d0 + 64];
  *(float4*)&s2v[4] = *(const float4*)&sinT[s * D_ + d0 + 68];
  short8 olo, ohi;
#pragma unroll
  for (int j = 0; j < 8; ++j) {
    const float x1 = bf2f((u16)lo[j]), x2 = bf2f((u16)hv[j]);
    olo[j] = (short)f2bf((x1 * c1v[j] - x2 * s1v[j]) * sc);
    ohi[j] = (short)f2bf((x2 * c2v[j] + x1 * s2v[j]) * sc);
  }
  *(short8*)&T[base + d0] = olo;
  *(short8*)&T[base + d0 + 64] = ohi;
}

// ---------------------------------------------------------------- V [B,H,S,D] -> VT [B,H,D,S]
__global__ void transpose64(const u16* __restrict__ V, u16* __restrict__ VT) {
  __shared__ alignas(16) u16 t[64][72];
  const int bh = blockIdx.z, st = blockIdx.y * 64, dt = blockIdx.x * 64;
  const u16* Vp = V + (size_t)bh * S_ * D_;
  u16* Tp = VT + (size_t)bh * D_ * S_;
  const int tid = threadIdx.x;
#pragma unroll
  for (int p = 0; p < 2; ++p) {
    const int idx = p * 256 + tid;
    const int r = idx >> 3, c8 = (idx & 7) * 8;
    *(short8*)&t[r][c8] = *(const short8*)&Vp[(size_t)(st + r) * D_ + dt + c8];
  }
  __syncthreads();
#pragma unroll
  for (int p = 0; p < 2; ++p) {
    const int idx = p * 256 + tid;
    const int dr = idx >> 3, s8 = (idx & 7) * 8;
    short8 v;
#pragma unroll
    for (int j = 0; j < 8; ++j) v[j] = t[s8 + j][dr];
    *(short8*)&Tp[(size_t)(dt + dr) * S_ + st + s8] = v;
  }
}

// ---------------------------------------------------------------- causal flash attention v4 (proven: 82 us)
// 8 waves x 32q, KV-parity split: waves 0-3 (grp A) even KV64 tiles, waves 4-7 (grp B) odd
// tiles, SAME 128 q-rows, concurrently (2 waves/SIMD). Each group has its own double-buffered
// K/V LDS stream. nt = 2t+2 (even) -> both groups do exactly t+1 steps: barriers uniform.
// Partial (m,l,O) merged through LDS at segment end. mr init = 0 (not -1e30) so a fully
// causal-masked first tile in group B yields p = exp2(-1e30-0) = 0, not exp2(0) = 1.
__launch_bounds__(512, 2)
__global__ void attn_fwd(const u16* __restrict__ Q, const u16* __restrict__ Kt,
                         const u16* __restrict__ VT, u16* __restrict__ Out) {
  // SB[stream][buf]: K tile [64][128] (8192 u16) then V^T tile [128][64] (8192 u16)
  __shared__ alignas(16) u16 SB[2][2][16384];
  __shared__ float MLB[4][64][2];
  const int tid = threadIdx.x, wave = tid >> 6, lane = tid & 63;
  // bijective XCD swizzle (256 % 8 == 0): 4 heads per XCD
  const int hw = blockIdx.x;
  const int lid = (hw & 7) * 32 + (hw >> 3);
  const int p = lid & 7, bh = lid >> 3;
  const int bb = bh >> 4, h = bh & 15;
  const u16* Qh = Q + (size_t)bh * S_ * D_;
  const u16* Kh = Kt + (size_t)bh * S_ * D_;
  const u16* Vh = VT + (size_t)bh * D_ * S_;
  const int grp = wave >> 2, w4 = wave & 3;
  const int l31 = lane & 31, hi = lane >> 5;

  auto stage = [&](int buf, int kv0) {   // 4 waves of my group stage my stream
#pragma unroll
    for (int pp = 0; pp < 4; ++pp) {
      const int g = pp * 4 + w4;       // 0..15 (wave-uniform)
      const int c = g * 64 + lane;     // 0..1023
      const int srow = c >> 4, dch = c & 15;
      GLD16(Kh + (size_t)(kv0 + srow) * D_ + ((dch ^ (srow & 7)) * 8), &SB[grp][buf][g * 512]);
      const int drow = c >> 3, sch = c & 7;
      GLD16(Vh + (size_t)drow * S_ + kv0 + ((sch ^ (drow & 7)) * 8), &SB[grp][buf][8192 + g * 512]);
    }
  };

  float* obuf = (float*)&SB[1][0][0];  // 64 KB merge region (stream 1, both buffers)

  const int qts[2] = {15 - p, p};
#pragma unroll 1
  for (int seg = 0; seg < 2; ++seg) {
    const int t = qts[seg];
    const int iters = t + 1;           // nt = 2t+2 KV64 tiles, split by parity
    const int q0 = t * 128 + w4 * 32;
    const int qg = q0 + l31;

    // Q fragments (B-operand): lane holds Q[qg][m*16 + hi*8 + j], j=0..7
    short8 qf[8];
#pragma unroll
    for (int m = 0; m < 8; ++m)
      qf[m] = *(const short8*)&Qh[(size_t)qg * D_ + m * 16 + hi * 8];

    f32x16 od[4] = {};   // out^T: od[dt], d = dt*32 + (reg&3)+8*(reg>>2)+4*hi, col q = l31
    float mr = 0.f, lsum = 0.f;        // mr init 0: see header comment

    stage(0, grp * 64);                // my first tile = tile grp
    int cur = 0;

    for (int i = 0; i < iters; ++i) {
      __syncthreads();  // both streams' buf[cur] staged; prior reads of buf[cur^1] done
      if (i + 1 < iters) stage(cur ^ 1, (2 * (i + 1) + grp) * 64);
      const int kv0 = (2 * i + grp) * 64;
      const u16* Kc = &SB[grp][cur][0];
      const u16* Vc = &SB[grp][cur][8192];

      // QK^T swapped: S^T[k][q], two 32-kv halves
      f32x16 s0 = {}, s1 = {};
      __builtin_amdgcn_s_setprio(1);
#pragma unroll
      for (int m = 0; m < 8; ++m) {
        const int col = m * 16 + hi * 8;
        const int sw = (l31 & 7) << 3;
        short8 k0 = *(const short8*)&Kc[l31 * 128 + (col ^ sw)];
        short8 k1 = *(const short8*)&Kc[(32 + l31) * 128 + (col ^ sw)];
        s0 = __builtin_amdgcn_mfma_f32_32x32x16_bf16(k0, qf[m], s0, 0, 0, 0);
        s1 = __builtin_amdgcn_mfma_f32_32x32x16_bf16(k1, qf[m], s1, 0, 0, 0);
      }
      __builtin_amdgcn_s_setprio(0);

      // causal mask (only tiles overlapping this wave's diagonal)
      if (kv0 + 63 > q0) {
#pragma unroll
        for (int r = 0; r < 16; ++r) {
          const int k0g = kv0 + (r & 3) + 8 * (r >> 2) + 4 * hi;
          if (k0g > qg)      s0[r] = -1e30f;
          if (k0g + 32 > qg) s1[r] = -1e30f;
        }
      }

      // online softmax (scores already in log2 units via pre-scaled Q)
      float mloc = s0[0];
#pragma unroll
      for (int r = 1; r < 16; ++r) mloc = fmaxf(mloc, s0[r]);
#pragma unroll
      for (int r = 0; r < 16; ++r) mloc = fmaxf(mloc, s1[r]);
      const float mx = fmaxf(mloc, __shfl_xor(mloc, 32));
      const bool need = !__all(mx <= mr + 8.f);   // defer-max (T13)
      float corr = 1.f;
      if (need) {
        const float mnew = fmaxf(mr, mx);
        corr = exp2f(mr - mnew);
        mr = mnew;
      }
      float sloc = 0.f;
#pragma unroll
      for (int r = 0; r < 16; ++r) { s0[r] = exp2f(s0[r] - mr); sloc += s0[r]; }
#pragma unroll
      for (int r = 0; r < 16; ++r) { s1[r] = exp2f(s1[r] - mr); sloc += s1[r]; }
      const float rsum = sloc + __shfl_xor(sloc, 32);
      lsum = lsum * corr + rsum;
      if (need) {
#pragma unroll
        for (int dt = 0; dt < 4; ++dt)
#pragma unroll
          for (int r = 0; r < 16; ++r) od[dt][r] *= corr;
      }

      // pack P to bf16 words: W[half][c][pr] covers k32 = 8c + 4hi + {2pr, 2pr+1}
      unsigned W0[4][2], W1[4][2];
#pragma unroll
      for (int c = 0; c < 4; ++c)
#pragma unroll
        for (int pr = 0; pr < 2; ++pr) {
          asm("v_cvt_pk_bf16_f32 %0, %1, %2"
              : "=v"(W0[c][pr]) : "v"(s0[4 * c + 2 * pr]), "v"(s0[4 * c + 2 * pr + 1]));
          asm("v_cvt_pk_bf16_f32 %0, %1, %2"
              : "=v"(W1[c][pr]) : "v"(s1[4 * c + 2 * pr]), "v"(s1[4 * c + 2 * pr + 1]));
        }

      // PV: out^T += V^T * P^T ; B-frag for group kk needs k = kk*16 + hi*8 + j
      __builtin_amdgcn_s_setprio(1);
#pragma unroll
      for (int kk = 0; kk < 4; ++kk) {
        const int cown = 2 * (kk & 1) + hi, csend = 2 * (kk & 1) + 1 - hi;
        unsigned o0, o1, sd0, sd1;
        if (kk < 2) { o0 = W0[cown][0]; o1 = W0[cown][1]; sd0 = W0[csend][0]; sd1 = W0[csend][1]; }
        else        { o0 = W1[cown][0]; o1 = W1[cown][1]; sd0 = W1[csend][0]; sd1 = W1[csend][1]; }
        const unsigned r0 = (unsigned)__shfl_xor((int)sd0, 32);
        const unsigned r1 = (unsigned)__shfl_xor((int)sd1, 32);
        uint4 bw;
        if (hi == 0) bw = make_uint4(o0, o1, r0, r1);
        else         bw = make_uint4(r0, r1, o0, o1);
        const short8 pf = *(const short8*)&bw;
        const int slot = 2 * kk + hi;
#pragma unroll
        for (int dt = 0; dt < 4; ++dt) {
          const int row = dt * 32 + l31;
          const short8 vf = *(const short8*)&Vc[row * 64 + ((slot ^ (row & 7)) * 8)];
          od[dt] = __builtin_amdgcn_mfma_f32_32x32x16_bf16(vf, pf, od[dt], 0, 0, 0);
        }
      }
      __builtin_amdgcn_s_setprio(0);
      cur ^= 1;
    }

    // ---- merge the two parity partials (group B -> LDS -> group A combines) ----
    __syncthreads();                     // all computes done; stream-1 LDS reusable
    if (grp == 1) {
      MLB[w4][lane][0] = mr;
      MLB[w4][lane][1] = lsum;
#pragma unroll
      for (int dt = 0; dt < 4; ++dt)
#pragma unroll
        for (int r = 0; r < 16; ++r)
          obuf[(dt * 16 + r) * 256 + w4 * 64 + lane] = od[dt][r];  // lane-major: conflict-free
    }
    __syncthreads();
    if (grp == 0) {
      const float mB = MLB[w4][lane][0];
      const float lB = MLB[w4][lane][1];
      const float m = fmaxf(mr, mB);
      const float aA = exp2f(mr - m), aB = exp2f(mB - m);
      lsum = lsum * aA + lB * aB;
#pragma unroll
      for (int dt = 0; dt < 4; ++dt)
#pragma unroll
        for (int r = 0; r < 16; ++r)
          od[dt][r] = od[dt][r] * aA + obuf[(dt * 16 + r) * 256 + w4 * 64 + lane] * aB;

      // finalize: o /= l, write bf16 to attn buffer laid out [B,S,E]
      const float inv = 1.f / lsum;
      const size_t obase = ((size_t)bb * S_ + qg) * E_ + h * D_;
#pragma unroll
      for (int dt = 0; dt < 4; ++dt)
#pragma unroll
        for (int g = 0; g < 4; ++g) {
          ushort4 w;
          w.x = f2bf(od[dt][4 * g + 0] * inv);
          w.y = f2bf(od[dt][4 * g + 1] * inv);
          w.z = f2bf(od[dt][4 * g + 2] * inv);
          w.w = f2bf(od[dt][4 * g + 3] * inv);
          *(ushort4*)&Out[obase + dt * 32 + 8 * g + 4 * hi] = w;
        }
    }
    __syncthreads();                     // merge reads done before next seg restages SB
  }
}

// ---------------------------------------------------------------- launcher
extern "C" void kernel_launch(void* const* d_in, const int* in_sizes, int n_in,
                              void* d_out, int out_size, void* d_ws, size_t ws_size,
                              hipStream_t stream) {
  const float* x    = (const float*)d_in[0];
  const float* cosT = (const float*)d_in[1];
  const float* sinT = (const float*)d_in[2];
  const float* Wq   = (const float*)d_in[3];
  const float* Wk   = (const float*)d_in[4];
  const float* Wv   = (const float*)d_in[5];
  const float* Wo   = (const float*)d_in[6];
  float* out = (float*)d_out;

  const size_t NX = (size_t)B_ * S_ * E_;  // 8388608
  const size_t NW = (size_t)E_ * E_;       // 4194304
  u16* ws  = (u16*)d_ws;
  u16* xb  = ws;
  u16* Wqb = xb + NX;        // [Wq;Wk;Wv] contiguous -> fused [6144][2048]
  u16* Wkb = Wqb + NW;
  u16* Wvb = Wkb + NW;
  u16* Wob = Wvb + NW;
  u16* Qb  = Wob + NW;       // Qb, Kb, Vb contiguous (gemm MODE 0 writes tz*NX offsets)
  u16* Kb  = Qb + NX;
  u16* Vb  = Kb + NX;
  u16* VTb = Vb + NX;
  u16* Ab  = VTb + NX;

  cast_bf16<<<(int)(NX / 4 / 256), 256, 0, stream>>>((const float4*)x, (ushort4*)xb, (int)(NX / 4));
  cast4_bf16<<<dim3((int)(NW / 4 / 256), 4), 256, 0, stream>>>(
      (const float4*)Wq, (const float4*)Wk, (const float4*)Wv, (const float4*)Wo,
      (ushort4*)Wqb, (ushort4*)Wkb, (ushort4*)Wvb, (ushort4*)Wob, (int)(NW / 4));

  // fused QKV projection: [4096,2048] x [6144,2048]^T -> Q,K,V all [B,H,S,D]
  gemm256<0><<<dim3(768), 512, 0, stream>>>(xb, Wqb, Qb, M_, 3 * E_, E_, 3);

  rope2_k<<<dim3((B_ * H_ * S_ * 8) / 256, 2), 256, 0, stream>>>(Qb, Kb, cosT, sinT);

  transpose64<<<dim3(D_ / 64, S_ / 64, B_ * H_), 256, 0, stream>>>(Vb, VTb);

  attn_fwd<<<dim3(256), 512, 0, stream>>>(Qb, Kb, VTb, Ab);

  gemm256<1><<<dim3(256), 512, 0, stream>>>(Ab, Wob, out, M_, E_, E_, 1);
}

// Round 10
// 248.986 us; speedup vs baseline: 1.2757x; 1.0920x over previous
//
#include <hip/hip_runtime.h>
#include <stdint.h>

typedef unsigned short u16;
typedef __attribute__((ext_vector_type(8))) short short8;
typedef __attribute__((ext_vector_type(4))) float f32x4;
typedef __attribute__((ext_vector_type(16))) float f32x16;

#define B_ 2
#define S_ 2048
#define E_ 2048
#define H_ 16
#define D_ 128
#define M_ 4096

__device__ __forceinline__ u16 f2bf(float f) {
  unsigned u = __float_as_uint(f);
  u = u + 0x7FFFu + ((u >> 16) & 1u);
  return (u16)(u >> 16);
}
__device__ __forceinline__ float bf2f(u16 h) {
  return __uint_as_float(((unsigned)h) << 16);
}

// async global->LDS, 16B per lane; LDS dest is wave-uniform base + lane*16
#define GLD16(gp, lp) __builtin_amdgcn_global_load_lds(                      \
    (__attribute__((address_space(1))) void*)(gp),                           \
    (__attribute__((address_space(3))) void*)(lp), 16, 0, 0)

// ---------------------------------------------------------------- cast f32->bf16
__global__ void cast_bf16(const float4* __restrict__ src, ushort4* __restrict__ dst, int n4) {
  int i = blockIdx.x * 256 + threadIdx.x;
  if (i < n4) {
    float4 v = src[i];
    ushort4 o;
    o.x = f2bf(v.x); o.y = f2bf(v.y); o.z = f2bf(v.z); o.w = f2bf(v.w);
    dst[i] = o;
  }
}

// 4 weight casts in one launch (blockIdx.y selects the tensor); o0..o2 contiguous -> [Wq;Wk;Wv]
__global__ void cast4_bf16(const float4* __restrict__ w0, const float4* __restrict__ w1,
                           const float4* __restrict__ w2, const float4* __restrict__ w3,
                           ushort4* __restrict__ o0, ushort4* __restrict__ o1,
                           ushort4* __restrict__ o2, ushort4* __restrict__ o3, int n4) {
  const int i = blockIdx.x * 256 + threadIdx.x;
  if (i >= n4) return;
  const float4* s; ushort4* d;
  switch (blockIdx.y) {
    case 0: s = w0; d = o0; break;
    case 1: s = w1; d = o1; break;
    case 2: s = w2; d = o2; break;
    default: s = w3; d = o3; break;
  }
  float4 v = s[i];
  ushort4 o;
  o.x = f2bf(v.x); o.y = f2bf(v.y); o.z = f2bf(v.z); o.w = f2bf(v.w);
  d[i] = o;
}

// ---------------------------------------------------------------- GEMM v4: phased, 2 barriers/tile,
// fused RoPE + V-transpose epilogue (MODE 0).
// C = A[M,K] @ W[N,K]^T.  BM=128, BN=256, BK=64. 8 waves, per-wave 64x64 output.
// 3-deep LDS ring (144 KB flat SMEM). Per K-tile TWO phases:
//   {readA frags + stage0 -> BAR -> 16 MFMA} {readB frags + stage1 -> vmcnt(6) lgkmcnt(0) -> BAR -> 16 MFMA}
// Barrier audit: staging targets sb != cur so phase-A reads crossing BAR1 are safe; phase-B reads
// are drained by lgkmcnt(0) BEFORE BAR2 (next tile's stage0 re-targets cur -> must not race).
// vmcnt(6): at tile t's wait, own outstanding = tile t+2's 6 issues -> <=6 left certifies t+1 staged.
// T2: XOR(chunk,row&7) swizzle via inverse-permuted global source (conflicts measured 0).
// XCD swizzle: column bands (bxpx panels/XCD).
// MODE 0 epilogue: C-tile (128 rows x 2 full heads) -> LDS [128][272] -> tz 0/1: NeoX rope
//   (pair d,d+64 intra-tile) + Q pre-scale, write [B,H,S,D]; tz 2: write V transposed [B,H,D,S].
// MODE 1: direct f32 row-major store.
template <int MODE>
__launch_bounds__(512, 1)
__global__ void gemm256(const u16* __restrict__ A, const u16* __restrict__ Bw,
                        void* __restrict__ Cp, int M, int N, int K, int bxpx,
                        const float* __restrict__ cosT, const float* __restrict__ sinT) {
  __shared__ alignas(16) u16 SMEM[73728];   // 144 KB: LA 3x8192 u16 | LB 3x16384 u16
  u16* const LA = SMEM;
  u16* const LB = SMEM + 24576;
  const int tid = threadIdx.x, wave = tid >> 6, lane = tid & 63;
  const int xcd = blockIdx.x & 7;
  const int j = blockIdx.x >> 3;
  const int bx = xcd * bxpx + (j % bxpx);
  const int by = j / bxpx;
  const int m0 = by * 128, n0 = bx * 256;
  const int wm = (wave >> 2) * 64, wn = (wave & 3) * 64;
  const int lrow = lane & 15, lq = lane >> 4;

  auto stage0 = [&](int buf, int kt) {   // A tile (2 issues) + B issue 0
    const int k0 = kt * 64;
#pragma unroll
    for (int i = 0; i < 2; ++i) {
      const int c = i * 512 + tid;
      const int row = c >> 3, k = c & 7;
      GLD16(A + (size_t)(m0 + row) * K + k0 + ((k ^ (row & 7)) * 8),
            LA + buf * 8192 + i * 4096 + wave * 512);
    }
    {
      const int c = tid;
      const int row = c >> 3, k = c & 7;
      GLD16(Bw + (size_t)(n0 + row) * K + k0 + ((k ^ (row & 7)) * 8),
            LB + buf * 16384 + wave * 512);
    }
  };
  auto stage1 = [&](int buf, int kt) {   // B issues 1..3
    const int k0 = kt * 64;
#pragma unroll
    for (int i = 1; i < 4; ++i) {
      const int c = i * 512 + tid;
      const int row = c >> 3, k = c & 7;
      GLD16(Bw + (size_t)(n0 + row) * K + k0 + ((k ^ (row & 7)) * 8),
            LB + buf * 16384 + i * 4096 + wave * 512);
    }
  };

  f32x4 acc[4][4] = {};
  const int NT = K >> 6;                 // 32
  stage0(0, 0); stage1(0, 0);
  stage0(1, 1); stage1(1, 1);
  asm volatile("s_waitcnt vmcnt(6) lgkmcnt(0)" ::: "memory");  // tile 0 staged
  __builtin_amdgcn_sched_barrier(0);
  __builtin_amdgcn_s_barrier();

  for (int t = 0; t < NT; ++t) {
    const int cur = t % 3;
    const int sb = (t + 2) % 3;
    const bool dostage = (t + 2) < NT;

    // ===== phase A (k-chunk 0) =====
    short8 a0[4], b0[4];
#pragma unroll
    for (int m = 0; m < 4; ++m) {
      const int row = wm + m * 16 + lrow;
      a0[m] = *(const short8*)&LA[cur * 8192 + row * 64 + ((lq ^ (row & 7)) * 8)];
    }
#pragma unroll
    for (int n = 0; n < 4; ++n) {
      const int row = wn + n * 16 + lrow;
      b0[n] = *(const short8*)&LB[cur * 16384 + row * 64 + ((lq ^ (row & 7)) * 8)];
    }
    if (dostage) stage0(sb, t + 2);
    __builtin_amdgcn_sched_barrier(0);
    __builtin_amdgcn_s_barrier();
    __builtin_amdgcn_sched_barrier(0);
    __builtin_amdgcn_s_setprio(1);
#pragma unroll
    for (int m = 0; m < 4; ++m)
#pragma unroll
      for (int n = 0; n < 4; ++n)
        acc[m][n] = __builtin_amdgcn_mfma_f32_16x16x32_bf16(a0[m], b0[n], acc[m][n], 0, 0, 0);
    __builtin_amdgcn_s_setprio(0);

    // ===== phase B (k-chunk 1) =====
    short8 a1[4], b1[4];
#pragma unroll
    for (int m = 0; m < 4; ++m) {
      const int row = wm + m * 16 + lrow;
      a1[m] = *(const short8*)&LA[cur * 8192 + row * 64 + (((4 + lq) ^ (row & 7)) * 8)];
    }
#pragma unroll
    for (int n = 0; n < 4; ++n) {
      const int row = wn + n * 16 + lrow;
      b1[n] = *(const short8*)&LB[cur * 16384 + row * 64 + (((4 + lq) ^ (row & 7)) * 8)];
    }
    if (dostage) stage1(sb, t + 2);
    if (t < NT - 2) { asm volatile("s_waitcnt vmcnt(6) lgkmcnt(0)" ::: "memory"); }
    else            { asm volatile("s_waitcnt vmcnt(0) lgkmcnt(0)" ::: "memory"); }
    __builtin_amdgcn_sched_barrier(0);
    __builtin_amdgcn_s_barrier();
    __builtin_amdgcn_sched_barrier(0);
    __builtin_amdgcn_s_setprio(1);
#pragma unroll
    for (int m = 0; m < 4; ++m)
#pragma unroll
      for (int n = 0; n < 4; ++n)
        acc[m][n] = __builtin_amdgcn_mfma_f32_16x16x32_bf16(a1[m], b1[n], acc[m][n], 0, 0, 0);
    __builtin_amdgcn_s_setprio(0);
  }

  const int rbase = lq * 4;  // C/D: col = lane&15, row = (lane>>4)*4 + r
  if (MODE == 1) {
#pragma unroll
    for (int m = 0; m < 4; ++m)
#pragma unroll
      for (int n = 0; n < 4; ++n)
#pragma unroll
        for (int r = 0; r < 4; ++r) {
          const int mm = m0 + wm + m * 16 + rbase + r;
          const int nn = n0 + wn + n * 16 + lrow;
          ((float*)Cp)[(size_t)mm * N + nn] = acc[m][n][r];
        }
    return;
  }

  // ===== MODE 0 epilogue: C tile -> LDS -> fused rope / V-transpose =====
  // All waves passed final BAR2 with lgkmcnt(0)+vmcnt(0) drained -> SMEM free to overwrite.
  u16* ct = SMEM;                        // [128][272] bf16 (stride 272 breaks pow2 banks)
#pragma unroll
  for (int m = 0; m < 4; ++m)
#pragma unroll
    for (int n = 0; n < 4; ++n)
#pragma unroll
      for (int r = 0; r < 4; ++r)
        ct[(wm + m * 16 + rbase + r) * 272 + wn + n * 16 + lrow] = f2bf(acc[m][n][r]);
  __syncthreads();

  const int tz = n0 >> 11;               // 0=Q 1=K 2=V (block-uniform)
  const int bb = m0 >> 11, s0 = m0 & (S_ - 1);
  const int h0 = (n0 >> 7) & 15;
  const size_t NXc = (size_t)B_ * S_ * E_;
  u16* dst = (u16*)Cp + (size_t)tz * NXc;

  if (tz < 2) {
    // NeoX rope; Q additionally pre-scaled by (1/sqrt(D))*log2(e)
    const float sc = (tz == 0) ? 0.12751744154f : 1.f;
#pragma unroll
    for (int i = 0; i < 8; ++i) {
      const int idx = i * 512 + tid;           // 4096 tasks = 128 rows x 32 col-chunks
      const int row = idx >> 5, c8 = (idx & 31) * 8;
      const int head = c8 >> 7, hd = c8 & 127;
      const int s = s0 + row;
      short8 self = *(const short8*)&ct[row * 272 + c8];
      short8 part = *(const short8*)&ct[row * 272 + (c8 ^ 64)];  // d,d+64 pair (same head)
      float4 cv0 = *(const float4*)&cosT[s * D_ + hd];
      float4 cv1 = *(const float4*)&cosT[s * D_ + hd + 4];
      float4 sv0 = *(const float4*)&sinT[s * D_ + hd];
      float4 sv1 = *(const float4*)&sinT[s * D_ + hd + 4];
      float cv[8] = {cv0.x, cv0.y, cv0.z, cv0.w, cv1.x, cv1.y, cv1.z, cv1.w};
      float sv[8] = {sv0.x, sv0.y, sv0.z, sv0.w, sv1.x, sv1.y, sv1.z, sv1.w};
      short8 o;
      if (hd < 64) {
#pragma unroll
        for (int jj = 0; jj < 8; ++jj) {
          const float x1 = bf2f((u16)self[jj]), x2 = bf2f((u16)part[jj]);
          o[jj] = (short)f2bf((x1 * cv[jj] - x2 * sv[jj]) * sc);
        }
      } else {
#pragma unroll
        for (int jj = 0; jj < 8; ++jj) {
          const float x2 = bf2f((u16)self[jj]), x1 = bf2f((u16)part[jj]);
          o[jj] = (short)f2bf((x2 * cv[jj] + x1 * sv[jj]) * sc);
        }
      }
      *(short8*)&dst[(((size_t)bb * H_ + h0 + head) * S_ + s) * D_ + hd] = o;
    }
  } else {
    // V: write transposed [B,H,D,S]
#pragma unroll
    for (int i = 0; i < 8; ++i) {
      const int task = i * 512 + tid;          // 4096 = 256 d-cols x 16 s-chunks
      const int dcol = task & 255, sch = task >> 8;
      short8 v;
#pragma unroll
      for (int jj = 0; jj < 8; ++jj) v[jj] = ct[(sch * 8 + jj) * 272 + dcol];
      const int h = h0 + (dcol >> 7), hd = dcol & 127;
      *(short8*)&dst[(((size_t)bb * H_ + h) * D_ + hd) * S_ + s0 + sch * 8] = v;
    }
  }
}

// ---------------------------------------------------------------- causal flash attention v4 (proven: 82 us)
// 8 waves x 32q, KV-parity split: waves 0-3 (grp A) even KV64 tiles, waves 4-7 (grp B) odd
// tiles, SAME 128 q-rows, concurrently (2 waves/SIMD). Each group has its own double-buffered
// K/V LDS stream. nt = 2t+2 (even) -> both groups do exactly t+1 steps: barriers uniform.
// Partial (m,l,O) merged through LDS at segment end. mr init = 0 (not -1e30) so a fully
// causal-masked first tile in group B yields p = exp2(-1e30-0) = 0, not exp2(0) = 1.
__launch_bounds__(512, 2)
__global__ void attn_fwd(const u16* __restrict__ Q, const u16* __restrict__ Kt,
                         const u16* __restrict__ VT, u16* __restrict__ Out) {
  // SB[stream][buf]: K tile [64][128] (8192 u16) then V^T tile [128][64] (8192 u16)
  __shared__ alignas(16) u16 SB[2][2][16384];
  __shared__ float MLB[4][64][2];
  const int tid = threadIdx.x, wave = tid >> 6, lane = tid & 63;
  // bijective XCD swizzle (256 % 8 == 0): 4 heads per XCD
  const int hw = blockIdx.x;
  const int lid = (hw & 7) * 32 + (hw >> 3);
  const int p = lid & 7, bh = lid >> 3;
  const int bb = bh >> 4, h = bh & 15;
  const u16* Qh = Q + (size_t)bh * S_ * D_;
  const u16* Kh = Kt + (size_t)bh * S_ * D_;
  const u16* Vh = VT + (size_t)bh * D_ * S_;
  const int grp = wave >> 2, w4 = wave & 3;
  const int l31 = lane & 31, hi = lane >> 5;

  auto stage = [&](int buf, int kv0) {   // 4 waves of my group stage my stream
#pragma unroll
    for (int pp = 0; pp < 4; ++pp) {
      const int g = pp * 4 + w4;       // 0..15 (wave-uniform)
      const int c = g * 64 + lane;     // 0..1023
      const int srow = c >> 4, dch = c & 15;
      GLD16(Kh + (size_t)(kv0 + srow) * D_ + ((dch ^ (srow & 7)) * 8), &SB[grp][buf][g * 512]);
      const int drow = c >> 3, sch = c & 7;
      GLD16(Vh + (size_t)drow * S_ + kv0 + ((sch ^ (drow & 7)) * 8), &SB[grp][buf][8192 + g * 512]);
    }
  };

  float* obuf = (float*)&SB[1][0][0];  // 64 KB merge region (stream 1, both buffers)

  const int qts[2] = {15 - p, p};
#pragma unroll 1
  for (int seg = 0; seg < 2; ++seg) {
    const int t = qts[seg];
    const int iters = t + 1;           // nt = 2t+2 KV64 tiles, split by parity
    const int q0 = t * 128 + w4 * 32;
    const int qg = q0 + l31;

    // Q fragments (B-operand): lane holds Q[qg][m*16 + hi*8 + j], j=0..7
    short8 qf[8];
#pragma unroll
    for (int m = 0; m < 8; ++m)
      qf[m] = *(const short8*)&Qh[(size_t)qg * D_ + m * 16 + hi * 8];

    f32x16 od[4] = {};   // out^T: od[dt], d = dt*32 + (reg&3)+8*(reg>>2)+4*hi, col q = l31
    float mr = 0.f, lsum = 0.f;        // mr init 0: see header comment

    stage(0, grp * 64);                // my first tile = tile grp
    int cur = 0;

    for (int i = 0; i < iters; ++i) {
      __syncthreads();  // both streams' buf[cur] staged; prior reads of buf[cur^1] done
      if (i + 1 < iters) stage(cur ^ 1, (2 * (i + 1) + grp) * 64);
      const int kv0 = (2 * i + grp) * 64;
      const u16* Kc = &SB[grp][cur][0];
      const u16* Vc = &SB[grp][cur][8192];

      // QK^T swapped: S^T[k][q], two 32-kv halves
      f32x16 s0 = {}, s1 = {};
      __builtin_amdgcn_s_setprio(1);
#pragma unroll
      for (int m = 0; m < 8; ++m) {
        const int col = m * 16 + hi * 8;
        const int sw = (l31 & 7) << 3;
        short8 k0 = *(const short8*)&Kc[l31 * 128 + (col ^ sw)];
        short8 k1 = *(const short8*)&Kc[(32 + l31) * 128 + (col ^ sw)];
        s0 = __builtin_amdgcn_mfma_f32_32x32x16_bf16(k0, qf[m], s0, 0, 0, 0);
        s1 = __builtin_amdgcn_mfma_f32_32x32x16_bf16(k1, qf[m], s1, 0, 0, 0);
      }
      __builtin_amdgcn_s_setprio(0);

      // causal mask (only tiles overlapping this wave's diagonal)
      if (kv0 + 63 > q0) {
#pragma unroll
        for (int r = 0; r < 16; ++r) {
          const int k0g = kv0 + (r & 3) + 8 * (r >> 2) + 4 * hi;
          if (k0g > qg)      s0[r] = -1e30f;
          if (k0g + 32 > qg) s1[r] = -1e30f;
        }
      }

      // online softmax (scores already in log2 units via pre-scaled Q)
      float mloc = s0[0];
#pragma unroll
      for (int r = 1; r < 16; ++r) mloc = fmaxf(mloc, s0[r]);
#pragma unroll
      for (int r = 0; r < 16; ++r) mloc = fmaxf(mloc, s1[r]);
      const float mx = fmaxf(mloc, __shfl_xor(mloc, 32));
      const bool need = !__all(mx <= mr + 8.f);   // defer-max (T13)
      float corr = 1.f;
      if (need) {
        const float mnew = fmaxf(mr, mx);
        corr = exp2f(mr - mnew);
        mr = mnew;
      }
      float sloc = 0.f;
#pragma unroll
      for (int r = 0; r < 16; ++r) { s0[r] = exp2f(s0[r] - mr); sloc += s0[r]; }
#pragma unroll
      for (int r = 0; r < 16; ++r) { s1[r] = exp2f(s1[r] - mr); sloc += s1[r]; }
      const float rsum = sloc + __shfl_xor(sloc, 32);
      lsum = lsum * corr + rsum;
      if (need) {
#pragma unroll
        for (int dt = 0; dt < 4; ++dt)
#pragma unroll
          for (int r = 0; r < 16; ++r) od[dt][r] *= corr;
      }

      // pack P to bf16 words: W[half][c][pr] covers k32 = 8c + 4hi + {2pr, 2pr+1}
      unsigned W0[4][2], W1[4][2];
#pragma unroll
      for (int c = 0; c < 4; ++c)
#pragma unroll
        for (int pr = 0; pr < 2; ++pr) {
          asm("v_cvt_pk_bf16_f32 %0, %1, %2"
              : "=v"(W0[c][pr]) : "v"(s0[4 * c + 2 * pr]), "v"(s0[4 * c + 2 * pr + 1]));
          asm("v_cvt_pk_bf16_f32 %0, %1, %2"
              : "=v"(W1[c][pr]) : "v"(s1[4 * c + 2 * pr]), "v"(s1[4 * c + 2 * pr + 1]));
        }

      // PV: out^T += V^T * P^T ; B-frag for group kk needs k = kk*16 + hi*8 + j
      __builtin_amdgcn_s_setprio(1);
#pragma unroll
      for (int kk = 0; kk < 4; ++kk) {
        const int cown = 2 * (kk & 1) + hi, csend = 2 * (kk & 1) + 1 - hi;
        unsigned o0, o1, sd0, sd1;
        if (kk < 2) { o0 = W0[cown][0]; o1 = W0[cown][1]; sd0 = W0[csend][0]; sd1 = W0[csend][1]; }
        else        { o0 = W1[cown][0]; o1 = W1[cown][1]; sd0 = W1[csend][0]; sd1 = W1[csend][1]; }
        const unsigned r0 = (unsigned)__shfl_xor((int)sd0, 32);
        const unsigned r1 = (unsigned)__shfl_xor((int)sd1, 32);
        uint4 bw;
        if (hi == 0) bw = make_uint4(o0, o1, r0, r1);
        else         bw = make_uint4(r0, r1, o0, o1);
        const short8 pf = *(const short8*)&bw;
        const int slot = 2 * kk + hi;
#pragma unroll
        for (int dt = 0; dt < 4; ++dt) {
          const int row = dt * 32 + l31;
          const short8 vf = *(const short8*)&Vc[row * 64 + ((slot ^ (row & 7)) * 8)];
          od[dt] = __builtin_amdgcn_mfma_f32_32x32x16_bf16(vf, pf, od[dt], 0, 0, 0);
        }
      }
      __builtin_amdgcn_s_setprio(0);
      cur ^= 1;
    }

    // ---- merge the two parity partials (group B -> LDS -> group A combines) ----
    __syncthreads();                     // all computes done; stream-1 LDS reusable
    if (grp == 1) {
      MLB[w4][lane][0] = mr;
      MLB[w4][lane][1] = lsum;
#pragma unroll
      for (int dt = 0; dt < 4; ++dt)
#pragma unroll
        for (int r = 0; r < 16; ++r)
          obuf[(dt * 16 + r) * 256 + w4 * 64 + lane] = od[dt][r];  // lane-major: conflict-free
    }
    __syncthreads();
    if (grp == 0) {
      const float mB = MLB[w4][lane][0];
      const float lB = MLB[w4][lane][1];
      const float m = fmaxf(mr, mB);
      const float aA = exp2f(mr - m), aB = exp2f(mB - m);
      lsum = lsum * aA + lB * aB;
#pragma unroll
      for (int dt = 0; dt < 4; ++dt)
#pragma unroll
        for (int r = 0; r < 16; ++r)
          od[dt][r] = od[dt][r] * aA + obuf[(dt * 16 + r) * 256 + w4 * 64 + lane] * aB;

      // finalize: o /= l, write bf16 to attn buffer laid out [B,S,E]
      const float inv = 1.f / lsum;
      const size_t obase = ((size_t)bb * S_ + qg) * E_ + h * D_;
#pragma unroll
      for (int dt = 0; dt < 4; ++dt)
#pragma unroll
        for (int g = 0; g < 4; ++g) {
          ushort4 w;
          w.x = f2bf(od[dt][4 * g + 0] * inv);
          w.y = f2bf(od[dt][4 * g + 1] * inv);
          w.z = f2bf(od[dt][4 * g + 2] * inv);
          w.w = f2bf(od[dt][4 * g + 3] * inv);
          *(ushort4*)&Out[obase + dt * 32 + 8 * g + 4 * hi] = w;
        }
    }
    __syncthreads();                     // merge reads done before next seg restages SB
  }
}

// ---------------------------------------------------------------- launcher
extern "C" void kernel_launch(void* const* d_in, const int* in_sizes, int n_in,
                              void* d_out, int out_size, void* d_ws, size_t ws_size,
                              hipStream_t stream) {
  const float* x    = (const float*)d_in[0];
  const float* cosT = (const float*)d_in[1];
  const float* sinT = (const float*)d_in[2];
  const float* Wq   = (const float*)d_in[3];
  const float* Wk   = (const float*)d_in[4];
  const float* Wv   = (const float*)d_in[5];
  const float* Wo   = (const float*)d_in[6];
  float* out = (float*)d_out;

  const size_t NX = (size_t)B_ * S_ * E_;  // 8388608
  const size_t NW = (size_t)E_ * E_;       // 4194304
  u16* ws  = (u16*)d_ws;
  u16* xb  = ws;
  u16* Wqb = xb + NX;        // [Wq;Wk;Wv] contiguous -> fused [6144][2048]
  u16* Wkb = Wqb + NW;
  u16* Wvb = Wkb + NW;
  u16* Wob = Wvb + NW;
  u16* Qb  = Wob + NW;       // Qb, Kb, VTb contiguous (gemm MODE 0 writes tz*NX offsets)
  u16* Kb  = Qb + NX;
  u16* VTb = Kb + NX;        // V written pre-transposed [B,H,D,S] by the epilogue
  u16* Ab  = VTb + NX;

  cast_bf16<<<(int)(NX / 4 / 256), 256, 0, stream>>>((const float4*)x, (ushort4*)xb, (int)(NX / 4));
  cast4_bf16<<<dim3((int)(NW / 4 / 256), 4), 256, 0, stream>>>(
      (const float4*)Wq, (const float4*)Wk, (const float4*)Wv, (const float4*)Wo,
      (ushort4*)Wqb, (ushort4*)Wkb, (ushort4*)Wvb, (ushort4*)Wob, (int)(NW / 4));

  // fused QKV projection + rope(Q,K) + V-transpose, all in one dispatch
  gemm256<0><<<dim3(768), 512, 0, stream>>>(xb, Wqb, Qb, M_, 3 * E_, E_, 3, cosT, sinT);

  attn_fwd<<<dim3(256), 512, 0, stream>>>(Qb, Kb, VTb, Ab);

  gemm256<1><<<dim3(256), 512, 0, stream>>>(Ab, Wob, out, M_, E_, E_, 1, nullptr, nullptr);
}